// Round 1
// baseline (142.295 us; speedup 1.0000x reference)
//
#include <hip/hip_runtime.h>

// SigScale: out[b, off_k + n] = x[b, off_k + n] * prod_{j=0..k-1} y[b, (n >> 3j) & 7]
// B=256, D=8, M=6, siglen = 8+64+512+4096+32768+262144 = 299592.
// Memory-bound: ~614 MB HBM traffic -> ~100 us floor at 6.3 TB/s.

#define SIGLEN 299592
#define NQ     74898   // SIGLEN / 4 (float4 units)

// Level start offsets in floats: L1=0, L2=8, L3=72, L4=584, L5=4680, L6=37448.

__global__ __launch_bounds__(256) void sigscale_kernel(
    const float* __restrict__ x,
    const float* __restrict__ y,
    float* __restrict__ out)
{
    // Per-level prefix-factor tables (products of y over 3-bit digit fields).
    __shared__ __align__(16) float f1[8];    // f1[a]    = y[a]
    __shared__ float f2[64];                 // f2[ab]   = y[a]*y[b]
    __shared__ float f3[512];                // f3[abc]  = y[a]*y[b]*y[c]

    const int b   = blockIdx.y;
    const int tid = threadIdx.x;

    if (tid < 8) f1[tid] = y[b * 8 + tid];
    __syncthreads();
    if (tid < 64) f2[tid] = f1[tid >> 3] * f1[tid & 7];
    __syncthreads();
    for (int i = tid; i < 512; i += 256) f3[i] = f2[i >> 3] * f1[i & 7];
    __syncthreads();

    const float4* __restrict__ xr   = reinterpret_cast<const float4*>(x + (size_t)b * SIGLEN);
    float4* __restrict__       orow = reinterpret_cast<float4*>(out + (size_t)b * SIGLEN);

    const int stride = gridDim.x * blockDim.x;
    for (int q = blockIdx.x * blockDim.x + tid; q < NQ; q += stride) {
        float4 v = xr[q];
        const int pos = q << 2;        // float index within the row
        int n;                         // element index within its level
        float g;                       // prefix factor (all digits except the lowest)
        if (pos >= 37448) {            // level 6: n has 18 bits, prefix p has 15
            n = pos - 37448;
            const int p = n >> 3;
            g = f3[p >> 6] * f2[p & 63];
        } else if (pos >= 4680) {      // level 5: prefix p has 12 bits
            n = pos - 4680;
            const int p = n >> 3;
            g = f3[p >> 3] * f1[p & 7];
        } else if (pos >= 584) {       // level 4: prefix p has 9 bits
            n = pos - 584;
            g = f3[n >> 3];
        } else if (pos >= 72) {        // level 3: prefix p has 6 bits
            n = pos - 72;
            g = f2[n >> 3];
        } else if (pos >= 8) {         // level 2: prefix p has 3 bits
            n = pos - 8;
            g = f1[n >> 3];
        } else {                       // level 1: no prefix
            n = pos;
            g = 1.0f;
        }
        // The 4 lanes of this float4 share the prefix; lowest digit = (n&4)|c.
        const float* yl = &f1[n & 4];
        float4 r;
        r.x = v.x * g * yl[0];
        r.y = v.y * g * yl[1];
        r.z = v.z * g * yl[2];
        r.w = v.w * g * yl[3];
        orow[q] = r;
    }
}

extern "C" void kernel_launch(void* const* d_in, const int* in_sizes, int n_in,
                              void* d_out, int out_size, void* d_ws, size_t ws_size,
                              hipStream_t stream) {
    const float* x = (const float*)d_in[0];
    const float* y = (const float*)d_in[1];
    float* out = (float*)d_out;
    // m (d_in[2]) is fixed at 6; layout constants are compiled in.

    dim3 grid(16, 256);   // 16 chunks per row x 256 rows = 4096 blocks
    sigscale_kernel<<<grid, 256, 0, stream>>>(x, y, out);
}

// Round 3
// 123.774 us; speedup vs baseline: 1.1496x; 1.1496x over previous
//
#include <hip/hip_runtime.h>

// SigScale: out[b, off_k + n] = x[b, off_k + n] * prod_{j} y[b, digit_j(n)]
// B=256, D=8, M=6, siglen = 299592 floats/row. Memory-bound (~614 MB HBM).
// Row byte pitch 1198368 ≡ 32 (mod 128) -> per-row quad phase s = (-2b)&7
// makes bulk float4 wave accesses 128B-aligned.

#define SIGLEN 299592
#define NQ     74898   // SIGLEN / 4

typedef float f4 __attribute__((ext_vector_type(4)));  // native vector: OK for nontemporal builtins

__device__ __forceinline__ float quad_g(int q,
                                        const float* __restrict__ f1,
                                        const float* __restrict__ f2,
                                        const float* __restrict__ f3,
                                        int& nout) {
    const int pos = q << 2;   // float index within the row
    int n; float g;
    if (pos >= 37448) {            // level 6: prefix p = n>>3 has 15 bits
        n = pos - 37448; const int p = n >> 3; g = f3[p >> 6] * f2[p & 63];
    } else if (pos >= 4680) {      // level 5: prefix 12 bits
        n = pos - 4680;  const int p = n >> 3; g = f3[p >> 3] * f1[p & 7];
    } else if (pos >= 584) {       // level 4: prefix 9 bits
        n = pos - 584;   g = f3[n >> 3];
    } else if (pos >= 72) {        // level 3
        n = pos - 72;    g = f2[n >> 3];
    } else if (pos >= 8) {         // level 2
        n = pos - 8;     g = f1[n >> 3];
    } else {                       // level 1
        n = pos;         g = 1.0f;
    }
    nout = n;
    return g;
}

__global__ __launch_bounds__(256) void sigscale_kernel(
    const float* __restrict__ x,
    const float* __restrict__ y,
    float* __restrict__ out)
{
    __shared__ __align__(16) float f1[8];   // y
    __shared__ float f2[64];                // y⊗y
    __shared__ float f3[512];               // y⊗y⊗y

    const int b   = blockIdx.y;
    const int tid = threadIdx.x;

    if (tid < 8) f1[tid] = y[b * 8 + tid];
    __syncthreads();
    if (tid < 64) f2[tid] = f1[tid >> 3] * f1[tid & 7];
    __syncthreads();
    for (int i = tid; i < 512; i += 256) f3[i] = f2[i >> 3] * f1[i & 7];
    __syncthreads();

    // low-digit factors held in registers (no LDS read in the hot loop)
    const f4 ylo = *reinterpret_cast<const f4*>(&f1[0]);
    const f4 yhi = *reinterpret_cast<const f4*>(&f1[4]);

    const f4* __restrict__ xr   = reinterpret_cast<const f4*>(x + (size_t)b * SIGLEN);
    f4* __restrict__       orow = reinterpret_cast<f4*>(out + (size_t)b * SIGLEN);

    // phase shift so bulk accesses are 128B-aligned: (32*b + 16*q) % 128 == 0
    const int s = (-(b << 1)) & 7;

    // head quads [0, s) — levels 1..2 only, handled by block x==0
    if (blockIdx.x == 0 && tid < s) {
        const int q = tid;
        int n; const float g = quad_g(q, f1, f2, f3, n);
        const f4 yl = (n & 4) ? yhi : ylo;
        const f4 v = xr[q];
        orow[q] = v * g * yl;
    }

    int q = s + blockIdx.x * 256 + tid;   // stride 2048 (8 blocks x 256 threads per row)

    // main loop: 4 batched float4 loads per iteration (64B in flight/thread)
    for (; q < NQ - 6144; q += 8192) {
        const int q0 = q, q1 = q + 2048, q2 = q + 4096, q3 = q + 6144;
        const f4 v0 = __builtin_nontemporal_load(&xr[q0]);
        const f4 v1 = __builtin_nontemporal_load(&xr[q1]);
        const f4 v2 = __builtin_nontemporal_load(&xr[q2]);
        const f4 v3 = __builtin_nontemporal_load(&xr[q3]);
        int n0, n1, n2, n3;
        const float g0 = quad_g(q0, f1, f2, f3, n0);
        const float g1 = quad_g(q1, f1, f2, f3, n1);
        const float g2 = quad_g(q2, f1, f2, f3, n2);
        const float g3 = quad_g(q3, f1, f2, f3, n3);
        const f4 a0 = (n0 & 4) ? yhi : ylo;
        const f4 a1 = (n1 & 4) ? yhi : ylo;
        const f4 a2 = (n2 & 4) ? yhi : ylo;
        const f4 a3 = (n3 & 4) ? yhi : ylo;
        const f4 r0 = v0 * g0 * a0;
        const f4 r1 = v1 * g1 * a1;
        const f4 r2 = v2 * g2 * a2;
        const f4 r3 = v3 * g3 * a3;
        __builtin_nontemporal_store(r0, &orow[q0]);
        __builtin_nontemporal_store(r1, &orow[q1]);
        __builtin_nontemporal_store(r2, &orow[q2]);
        __builtin_nontemporal_store(r3, &orow[q3]);
    }

    // tail singles
    for (; q < NQ; q += 2048) {
        int n; const float g = quad_g(q, f1, f2, f3, n);
        const f4 yl = (n & 4) ? yhi : ylo;
        const f4 v = __builtin_nontemporal_load(&xr[q]);
        const f4 r = v * g * yl;
        __builtin_nontemporal_store(r, &orow[q]);
    }
}

extern "C" void kernel_launch(void* const* d_in, const int* in_sizes, int n_in,
                              void* d_out, int out_size, void* d_ws, size_t ws_size,
                              hipStream_t stream) {
    const float* x = (const float*)d_in[0];
    const float* y = (const float*)d_in[1];
    float* out = (float*)d_out;

    dim3 grid(8, 256);   // 2048 blocks = 8 blocks/CU, exactly resident
    sigscale_kernel<<<grid, 256, 0, stream>>>(x, y, out);
}